// Round 1
// baseline (123.399 us; speedup 1.0000x reference)
//
#include <hip/hip_runtime.h>
#include <math.h>

// NUFFT type-2 exact NUDFT: out[b,c,k] = sum_{x,y} img[b,c,x,y] * exp(-i*(om_x*(x-64) + om_y*(y-64)))
// Strategy: lane<->k mapping, phase via complex geometric recurrence (no per-element sincos),
// image reads are wave-uniform broadcasts (L1/L2 resident, 2MB total).

constexpr int Bn = 2, Cn = 8, Kn = 2048, Hn = 128, Wn = 128;
constexpr int KPB = 64;          // k's per block (one wave-width)
constexpr int WAVES = 4;         // waves per block, each takes an x-slab
constexpr int XPW = Hn / WAVES;  // 32 rows per wave

template<int OUT_COMPLEX>
__global__ __launch_bounds__(256, 2)
void nufft_kernel(const float* __restrict__ img_re,
                  const float* __restrict__ img_im,
                  const float* __restrict__ traj,
                  float* __restrict__ out)
{
    const int blocks_per_bc = Kn / KPB;           // 32
    const int bc   = blockIdx.x / blocks_per_bc;  // 0..15 (b*C+c)
    const int kc   = blockIdx.x % blocks_per_bc;
    const int wave = threadIdx.x >> 6;
    const int lane = threadIdx.x & 63;
    const int k    = kc * KPB + lane;

    // kspace_traj layout: (B, C, 2, K)
    const float om_x = traj[(size_t)(bc * 2 + 0) * Kn + k];
    const float om_y = traj[(size_t)(bc * 2 + 1) * Kn + k];

    float s, c;
    // per-step phase factors exp(-i*om)
    sincosf(om_x, &s, &c);
    const float stepx_re = c, stepx_im = -s;
    sincosf(om_y, &s, &c);
    const float stepy_re = c, stepy_im = -s;

    const int x0 = wave * XPW;
    // row phase at x = x0: exp(-i*om_x*(x0-64))
    sincosf(-om_x * (float)(x0 - Hn / 2), &s, &c);
    float rowp_re = c, rowp_im = s;
    // column start phase at y = 0: exp(-i*om_y*(0-64)) = exp(+i*64*om_y)
    sincosf(om_y * (float)(Wn / 2), &s, &c);
    const float y0_re = c, y0_im = s;

    float acc_re = 0.f, acc_im = 0.f;

    const float* pre = img_re + (size_t)bc * Hn * Wn + (size_t)x0 * Wn;
    const float* pim = img_im + (size_t)bc * Hn * Wn + (size_t)x0 * Wn;

    for (int xr = 0; xr < XPW; ++xr) {
        // cur = rowp * y0  (phase at (x, y=0))
        float cur_re = rowp_re * y0_re - rowp_im * y0_im;
        float cur_im = rowp_re * y0_im + rowp_im * y0_re;
        #pragma unroll 8
        for (int y = 0; y < Wn; ++y) {
            const float ir = pre[y];   // wave-uniform broadcast load
            const float ii = pim[y];
            // acc += (ir + i*ii) * (cur_re + i*cur_im)
            acc_re = fmaf(ir, cur_re, acc_re);
            acc_re = fmaf(-ii, cur_im, acc_re);
            acc_im = fmaf(ir, cur_im, acc_im);
            acc_im = fmaf(ii, cur_re, acc_im);
            // cur *= stepy
            const float nr = fmaf(cur_re, stepy_re, -cur_im * stepy_im);
            cur_im         = fmaf(cur_re, stepy_im,  cur_im * stepy_re);
            cur_re = nr;
        }
        // rowp *= stepx
        const float nrr = fmaf(rowp_re, stepx_re, -rowp_im * stepx_im);
        rowp_im         = fmaf(rowp_re, stepx_im,  rowp_im * stepx_re);
        rowp_re = nrr;
        pre += Wn; pim += Wn;
    }

    // cross-wave reduction (4 partial sums per k)
    __shared__ float red_re[WAVES][KPB];
    __shared__ float red_im[WAVES][KPB];
    red_re[wave][lane] = acc_re;
    red_im[wave][lane] = acc_im;
    __syncthreads();

    if (threadIdx.x < KPB) {
        float r = 0.f, i2 = 0.f;
        #pragma unroll
        for (int w = 0; w < WAVES; ++w) {
            r  += red_re[w][threadIdx.x];
            i2 += red_im[w][threadIdx.x];
        }
        const int kk = kc * KPB + (int)threadIdx.x;
        if (OUT_COMPLEX) {
            out[((size_t)bc * Kn + kk) * 2 + 0] = r;
            out[((size_t)bc * Kn + kk) * 2 + 1] = i2;
        } else {
            out[(size_t)bc * Kn + kk] = r;   // harness kept only the real part
        }
    }
}

extern "C" void kernel_launch(void* const* d_in, const int* in_sizes, int n_in,
                              void* d_out, int out_size, void* d_ws, size_t ws_size,
                              hipStream_t stream) {
    const float* img_re = (const float*)d_in[0];
    const float* img_im = (const float*)d_in[1];
    const float* traj   = (const float*)d_in[2];
    float* out = (float*)d_out;

    dim3 grid(Bn * Cn * (Kn / KPB));  // 512 blocks -> 2 per CU
    dim3 block(WAVES * 64);           // 256 threads

    if (out_size == Bn * Cn * Kn * 2) {
        hipLaunchKernelGGL((nufft_kernel<1>), grid, block, 0, stream, img_re, img_im, traj, out);
    } else {
        hipLaunchKernelGGL((nufft_kernel<0>), grid, block, 0, stream, img_re, img_im, traj, out);
    }
}